// Round 1
// baseline (2099.282 us; speedup 1.0000x reference)
//
#include <hip/hip_runtime.h>
#include <math.h>

// Problem constants (X: [64, 512, 32, 32] fp32)
#define Nn   64
#define Cc   512
#define HWs  1024
#define CHW  (Cc * HWs)      // 524288
#define Mm   (Nn * HWs)      // 65536
#define EPSC 1e-5f

// ---------------------------------------------------------------------------
// K1: per-channel mean.  512 blocks (one per channel) x 256 threads.
// Each thread loads one float4 per n (1024 floats per n = 256 float4).
// ---------------------------------------------------------------------------
__global__ __launch_bounds__(256) void mean_kernel(const float* __restrict__ X,
                                                   float* __restrict__ mean) {
    const int c = blockIdx.x;
    const int t = threadIdx.x;
    float s = 0.f;
    for (int n = 0; n < Nn; ++n) {
        const float4* p = (const float4*)(X + (size_t)n * CHW + (size_t)c * HWs);
        float4 v = p[t];
        s += v.x + v.y + v.z + v.w;
    }
    __shared__ float red[256];
    red[t] = s;
    __syncthreads();
    for (int o = 128; o > 0; o >>= 1) {
        if (t < o) red[t] += red[t + o];
        __syncthreads();
    }
    if (t == 0) mean[c] = red[0] * (1.0f / Mm);
}

// ---------------------------------------------------------------------------
// K2: Gram matrix G = x @ x^T  (x is [512, 65536] laid out as 64 blocks of
// row-major [512,1024]).  Grid: (64 tiles of 64x64, 8 k-splits over n).
// Each block accumulates over 8 n-slices (k=8192) and atomicAdds its tile.
// ---------------------------------------------------------------------------
__global__ __launch_bounds__(256) void gram_kernel(const float* __restrict__ X,
                                                   float* __restrict__ G) {
    const int ti = blockIdx.x >> 3, tj = blockIdx.x & 7;
    const int i0 = ti << 6, j0 = tj << 6;
    const int n0 = blockIdx.y << 3;
    const int t  = threadIdx.x;
    const int tx = t & 15, ty = t >> 4;

    __shared__ float As[64][33];
    __shared__ float Bs[64][33];

    float acc[4][4] = {};

    const int lc  = t & 31;   // load col 0..31
    const int lr0 = t >> 5;   // load row base 0..7

    for (int n = n0; n < n0 + 8; ++n) {
        const float* Xn = X + (size_t)n * CHW;
        for (int hw0 = 0; hw0 < HWs; hw0 += 32) {
#pragma unroll
            for (int r = 0; r < 8; ++r) {
                const int row = lr0 + (r << 3);
                As[row][lc] = Xn[(size_t)(i0 + row) * HWs + hw0 + lc];
                Bs[row][lc] = Xn[(size_t)(j0 + row) * HWs + hw0 + lc];
            }
            __syncthreads();
#pragma unroll
            for (int k = 0; k < 32; ++k) {
                float a[4], b[4];
#pragma unroll
                for (int r = 0; r < 4; ++r) a[r] = As[(ty << 2) + r][k];
#pragma unroll
                for (int cn = 0; cn < 4; ++cn) b[cn] = Bs[(tx << 2) + cn][k];
#pragma unroll
                for (int r = 0; r < 4; ++r)
#pragma unroll
                    for (int cn = 0; cn < 4; ++cn) acc[r][cn] += a[r] * b[cn];
            }
            __syncthreads();
        }
    }
#pragma unroll
    for (int r = 0; r < 4; ++r)
#pragma unroll
        for (int cn = 0; cn < 4; ++cn)
            atomicAdd(&G[(size_t)(i0 + (ty << 2) + r) * Cc + j0 + (tx << 2) + cn],
                      acc[r][cn]);
}

// ---------------------------------------------------------------------------
// K3a: trace(Sigma) -> rTr, sqrt(rTr).  One block.
// Sigma = G/m - mean mean^T + eps*I
// ---------------------------------------------------------------------------
__global__ __launch_bounds__(256) void trace_kernel(const float* __restrict__ G,
                                                    const float* __restrict__ mean,
                                                    float* __restrict__ scal) {
    const int t = threadIdx.x;
    float s = 0.f;
    for (int i = t; i < Cc; i += 256)
        s += G[(size_t)i * Cc + i] * (1.0f / Mm) - mean[i] * mean[i];
    __shared__ float red[256];
    red[t] = s;
    __syncthreads();
    for (int o = 128; o > 0; o >>= 1) {
        if (t < o) red[t] += red[t + o];
        __syncthreads();
    }
    if (t == 0) {
        const float tr  = red[0] + (float)Cc * EPSC;
        const float rtr = 1.0f / tr;
        scal[0] = rtr;
        scal[1] = sqrtf(rtr);
    }
}

// ---------------------------------------------------------------------------
// K3b: Sigma_N = Sigma * rTr ; P = I.  262144 elements.
// ---------------------------------------------------------------------------
__global__ __launch_bounds__(256) void sigman_kernel(const float* __restrict__ G,
                                                     const float* __restrict__ mean,
                                                     const float* __restrict__ scal,
                                                     float* __restrict__ S,
                                                     float* __restrict__ P) {
    const int e = blockIdx.x * 256 + threadIdx.x;
    const int i = e >> 9, j = e & 511;
    const float rtr = scal[0];
    float sig = G[e] * (1.0f / Mm) - mean[i] * mean[j];
    if (i == j) sig += EPSC;
    S[e] = sig * rtr;
    P[e] = (i == j) ? 1.f : 0.f;
}

// ---------------------------------------------------------------------------
// K4: 512x512x512 fp32 matmul:  C = alpha*(A@B) + beta*D  (D may be null).
// 64 blocks of 64x64 tiles, 256 threads, 4x4 micro-tile, k-step 32.
// ---------------------------------------------------------------------------
__global__ __launch_bounds__(256) void mm512_kernel(const float* __restrict__ A,
                                                    const float* __restrict__ B,
                                                    float* __restrict__ C,
                                                    float alpha,
                                                    const float* __restrict__ D,
                                                    float beta) {
    const int ti = blockIdx.x >> 3, tj = blockIdx.x & 7;
    const int i0 = ti << 6, j0 = tj << 6;
    const int t  = threadIdx.x;
    const int tx = t & 15, ty = t >> 4;

    __shared__ float As[64][33];
    __shared__ float Bs[32][65];

    float acc[4][4] = {};

    const int lcA = t & 31, lrA = t >> 5;  // A tile 64x32
    const int lcB = t & 63, lrB = t >> 6;  // B tile 32x64

    for (int k0 = 0; k0 < 512; k0 += 32) {
#pragma unroll
        for (int r = 0; r < 8; ++r) {
            const int row = lrA + (r << 3);
            As[row][lcA] = A[(size_t)(i0 + row) * 512 + k0 + lcA];
        }
#pragma unroll
        for (int r = 0; r < 8; ++r) {
            const int row = lrB + (r << 2);
            Bs[row][lcB] = B[(size_t)(k0 + row) * 512 + j0 + lcB];
        }
        __syncthreads();
#pragma unroll
        for (int k = 0; k < 32; ++k) {
            float a[4], b[4];
#pragma unroll
            for (int r = 0; r < 4; ++r) a[r] = As[(ty << 2) + r][k];
#pragma unroll
            for (int cn = 0; cn < 4; ++cn) b[cn] = Bs[k][(tx << 2) + cn];
#pragma unroll
            for (int r = 0; r < 4; ++r)
#pragma unroll
                for (int cn = 0; cn < 4; ++cn) acc[r][cn] += a[r] * b[cn];
        }
        __syncthreads();
    }

#pragma unroll
    for (int r = 0; r < 4; ++r) {
        const size_t idx = (size_t)(i0 + (ty << 2) + r) * 512 + j0 + (tx << 2);
        float4 v;
        v.x = alpha * acc[r][0];
        v.y = alpha * acc[r][1];
        v.z = alpha * acc[r][2];
        v.w = alpha * acc[r][3];
        if (D) {
            const float4 d = *(const float4*)(D + idx);
            v.x += beta * d.x; v.y += beta * d.y; v.z += beta * d.z; v.w += beta * d.w;
        }
        *(float4*)(C + idx) = v;
    }
}

// ---------------------------------------------------------------------------
// K5: wmm[c] = sqrt(rTr) * sum_j P[c][j]*mean[j].  512 blocks x 128 threads.
// ---------------------------------------------------------------------------
__global__ __launch_bounds__(128) void wmm_kernel(const float* __restrict__ P,
                                                  const float* __restrict__ mean,
                                                  const float* __restrict__ scal,
                                                  float* __restrict__ wmm) {
    const int c = blockIdx.x, t = threadIdx.x;
    float s = 0.f;
    for (int j = t; j < Cc; j += 128) s += P[(size_t)c * Cc + j] * mean[j];
    __shared__ float red[128];
    red[t] = s;
    __syncthreads();
    for (int o = 64; o > 0; o >>= 1) {
        if (t < o) red[t] += red[t + o];
        __syncthreads();
    }
    if (t == 0) wmm[c] = red[0] * scal[1];
}

// ---------------------------------------------------------------------------
// K6: whiten.  out[n][c][hw] = sqrt(rTr)*(P @ x)[c][n*1024+hw] - wmm[c]
// Grid: (8 c-tiles, 16 hw-tiles, 64 n).  64x64 tile, 4x4 micro-tile.
// ---------------------------------------------------------------------------
__global__ __launch_bounds__(256) void whiten_kernel(const float* __restrict__ X,
                                                     const float* __restrict__ P,
                                                     const float* __restrict__ wmm,
                                                     const float* __restrict__ scal,
                                                     float* __restrict__ out) {
    const int c0 = blockIdx.x << 6;
    const int h0 = blockIdx.y << 6;
    const int n  = blockIdx.z;
    const int t  = threadIdx.x;
    const int tx = t & 15, ty = t >> 4;

    __shared__ float Ps[64][33];
    __shared__ float Xs[32][65];

    float acc[4][4] = {};

    const int lcA = t & 31, lrA = t >> 5;
    const int lcB = t & 63, lrB = t >> 6;

    const float* Xn = X + (size_t)n * CHW;

    for (int k0 = 0; k0 < 512; k0 += 32) {
#pragma unroll
        for (int r = 0; r < 8; ++r) {
            const int row = lrA + (r << 3);
            Ps[row][lcA] = P[(size_t)(c0 + row) * 512 + k0 + lcA];
        }
#pragma unroll
        for (int r = 0; r < 8; ++r) {
            const int row = lrB + (r << 2);
            Xs[row][lcB] = Xn[(size_t)(k0 + row) * HWs + h0 + lcB];
        }
        __syncthreads();
#pragma unroll
        for (int k = 0; k < 32; ++k) {
            float a[4], b[4];
#pragma unroll
            for (int r = 0; r < 4; ++r) a[r] = Ps[(ty << 2) + r][k];
#pragma unroll
            for (int cn = 0; cn < 4; ++cn) b[cn] = Xs[k][(tx << 2) + cn];
#pragma unroll
            for (int r = 0; r < 4; ++r)
#pragma unroll
                for (int cn = 0; cn < 4; ++cn) acc[r][cn] += a[r] * b[cn];
        }
        __syncthreads();
    }

    const float sr = scal[1];
#pragma unroll
    for (int r = 0; r < 4; ++r) {
        const int c = c0 + (ty << 2) + r;
        const float w = wmm[c];
        float4 v;
        v.x = sr * acc[r][0] - w;
        v.y = sr * acc[r][1] - w;
        v.z = sr * acc[r][2] - w;
        v.w = sr * acc[r][3] - w;
        *(float4*)(out + (size_t)n * CHW + (size_t)c * HWs + h0 + (tx << 2)) = v;
    }
}

// ---------------------------------------------------------------------------
extern "C" void kernel_launch(void* const* d_in, const int* in_sizes, int n_in,
                              void* d_out, int out_size, void* d_ws, size_t ws_size,
                              hipStream_t stream) {
    const float* X  = (const float*)d_in[0];
    float* out      = (float*)d_out;

    // workspace layout (floats): needs ~6.3 MB
    float* ws   = (float*)d_ws;
    float* mean = ws;               // 512
    float* wmm  = ws + 512;         // 512
    float* scal = ws + 1024;        // 2 (+pad to 2048)
    float* G    = ws + 2048;        // 512*512
    float* S    = G + 262144;       // Sigma_N
    float* Pa   = S + 262144;
    float* Pb   = Pa + 262144;
    float* P2   = Pb + 262144;
    float* P3   = P2 + 262144;

    mean_kernel<<<512, 256, 0, stream>>>(X, mean);
    hipMemsetAsync(G, 0, sizeof(float) * 262144, stream);
    gram_kernel<<<dim3(64, 8), 256, 0, stream>>>(X, G);
    trace_kernel<<<1, 256, 0, stream>>>(G, mean, scal);
    sigman_kernel<<<1024, 256, 0, stream>>>(G, mean, scal, S, Pa);

    float* P  = Pa;
    float* Pn = Pb;
    for (int it = 0; it < 5; ++it) {
        mm512_kernel<<<64, 256, 0, stream>>>(P, P, P2, 1.f, nullptr, 0.f);
        mm512_kernel<<<64, 256, 0, stream>>>(P2, P, P3, 1.f, nullptr, 0.f);
        mm512_kernel<<<64, 256, 0, stream>>>(P3, S, Pn, -0.5f, P, 1.5f);
        float* tmp = P; P = Pn; Pn = tmp;
    }

    wmm_kernel<<<512, 128, 0, stream>>>(P, mean, scal, wmm);
    whiten_kernel<<<dim3(8, 16, 64), 256, 0, stream>>>(X, P, wmm, scal, out);
}

// Round 2
// 864.045 us; speedup vs baseline: 2.4296x; 2.4296x over previous
//
#include <hip/hip_runtime.h>
#include <math.h>

// Problem constants (X: [64, 512, 32, 32] fp32)
#define Nn   64
#define Cc   512
#define HWs  1024
#define CHW  (Cc * HWs)      // 524288
#define Mm   (Nn * HWs)      // 65536
#define EPSC 1e-5f

typedef unsigned int   u32;
typedef unsigned short u16;
typedef __attribute__((ext_vector_type(8))) short  short8;   // 8 x bf16 = 4 VGPR
typedef __attribute__((ext_vector_type(4))) float  floatx4;

__device__ __forceinline__ u16 f2bf(float f) {
    u32 u = __float_as_uint(f);
    u += 0x7fff + ((u >> 16) & 1);   // RNE
    return (u16)(u >> 16);
}

__device__ __forceinline__ void gld_lds16(const u16* g, u16* l) {
    // async global->LDS, 16B per lane; LDS dest = wave-uniform base + lane*16
    __builtin_amdgcn_global_load_lds(
        (const __attribute__((address_space(1))) u32*)g,
        (__attribute__((address_space(3))) u32*)l, 16, 0, 0);
}

// ---------------------------------------------------------------------------
// K1: per-channel mean (fp32 read).  512 blocks x 256 threads.
// ---------------------------------------------------------------------------
__global__ __launch_bounds__(256) void mean_kernel(const float* __restrict__ X,
                                                   float* __restrict__ mean) {
    const int c = blockIdx.x;
    const int t = threadIdx.x;
    float s = 0.f;
    for (int n = 0; n < Nn; ++n) {
        const float4* p = (const float4*)(X + (size_t)n * CHW + (size_t)c * HWs);
        float4 v = p[t];
        s += v.x + v.y + v.z + v.w;
    }
    __shared__ float red[256];
    red[t] = s;
    __syncthreads();
    for (int o = 128; o > 0; o >>= 1) {
        if (t < o) red[t] += red[t + o];
        __syncthreads();
    }
    if (t == 0) mean[c] = red[0] * (1.0f / Mm);
}

// ---------------------------------------------------------------------------
// K0: fp32 -> bf16 convert (natural layout) + transposed copy Xt[n][hw][c].
// Grid (16 hw-tiles, 8 c-tiles, 64 n), 256 threads, 64x64 tile via LDS.
// ---------------------------------------------------------------------------
__global__ __launch_bounds__(256) void convert_transpose(const float* __restrict__ X,
                                                         u16* __restrict__ Xbf,
                                                         u16* __restrict__ Xt) {
    const int h0 = blockIdx.x << 6;
    const int c0 = blockIdx.y << 6;
    const int n  = blockIdx.z;
    const int t  = threadIdx.x;
    __shared__ u16 T[64][65];

    const float* Xn  = X   + (size_t)n * CHW;
    u16*         Xbn = Xbf + (size_t)n * CHW;
    u16*         Xtn = Xt  + (size_t)n * CHW;

    const int cl = t >> 4;          // 0..15
    const int h4 = (t & 15) << 2;   // 0,4,..,60
#pragma unroll
    for (int i = 0; i < 4; ++i) {
        const int c = cl + (i << 4);
        float4 v = *(const float4*)&Xn[(size_t)(c0 + c) * HWs + h0 + h4];
        u16 b0 = f2bf(v.x), b1 = f2bf(v.y), b2 = f2bf(v.z), b3 = f2bf(v.w);
        *(ushort4*)&Xbn[(size_t)(c0 + c) * HWs + h0 + h4] = make_ushort4(b0, b1, b2, b3);
        T[c][h4]     = b0;
        T[c][h4 + 1] = b1;
        T[c][h4 + 2] = b2;
        T[c][h4 + 3] = b3;
    }
    __syncthreads();
    const int hl = t >> 4;          // 0..15
    const int c4 = (t & 15) << 2;   // 0,4,..,60
#pragma unroll
    for (int i = 0; i < 4; ++i) {
        const int h = hl + (i << 4);
        ushort4 pk = make_ushort4(T[c4][h], T[c4 + 1][h], T[c4 + 2][h], T[c4 + 3][h]);
        *(ushort4*)&Xtn[(size_t)(h0 + h) * Cc + c0 + c4] = pk;
    }
}

// ---------------------------------------------------------------------------
// K2: Gram via bf16 MFMA, upper-triangle 128x128 tiles, split-K over n-pairs.
// Grid (10 tiles, 32 splits), 256 threads = 4 waves (2x2), 4x4 frags/wave.
// fp32 atomicAdd accumulation into G.
// ---------------------------------------------------------------------------
__global__ __launch_bounds__(256) void gram_mfma(const u16* __restrict__ Xbf,
                                                 float* __restrict__ G) {
    static const int TI[10] = {0,0,0,0,1,1,1,2,2,3};
    static const int TJ[10] = {0,1,2,3,1,2,3,2,3,3};
    const int i0 = TI[blockIdx.x] << 7;
    const int j0 = TJ[blockIdx.x] << 7;
    const int n0 = blockIdx.y << 1;           // 2 n per split
    const int t  = threadIdx.x;
    const int w  = t >> 6, l = t & 63;

    __shared__ u16 As[128 * 32];
    __shared__ u16 Bs[128 * 32];

    floatx4 acc[4][4];
#pragma unroll
    for (int mi = 0; mi < 4; ++mi)
#pragma unroll
        for (int ni = 0; ni < 4; ++ni) acc[mi][ni] = (floatx4){0.f, 0.f, 0.f, 0.f};

    const int lr = l >> 2;            // row within 16-row staging group
    const int lc = (l & 3) << 3;      // k element offset (0,8,16,24)
    const int wm = w >> 1, wn = w & 1;
    const int fm = l & 15, fq = l >> 4;

    for (int n = n0; n < n0 + 2; ++n) {
        const u16* Xn = Xbf + (size_t)n * CHW;
        for (int hw = 0; hw < HWs; hw += 32) {
#pragma unroll
            for (int p = 0; p < 2; ++p) {
                const int g   = w * 2 + p;            // staging group 0..7
                const int row = g * 16 + lr;
                gld_lds16(Xn + (size_t)(i0 + row) * HWs + hw + lc, &As[g * 512]);
                gld_lds16(Xn + (size_t)(j0 + row) * HWs + hw + lc, &Bs[g * 512]);
            }
            __syncthreads();
            short8 a[4], b[4];
#pragma unroll
            for (int mi = 0; mi < 4; ++mi)
                a[mi] = *(const short8*)&As[(wm * 64 + mi * 16 + fm) * 32 + fq * 8];
#pragma unroll
            for (int ni = 0; ni < 4; ++ni)
                b[ni] = *(const short8*)&Bs[(wn * 64 + ni * 16 + fm) * 32 + fq * 8];
#pragma unroll
            for (int mi = 0; mi < 4; ++mi)
#pragma unroll
                for (int ni = 0; ni < 4; ++ni)
                    acc[mi][ni] = __builtin_amdgcn_mfma_f32_16x16x32_bf16(
                        a[mi], b[ni], acc[mi][ni], 0, 0, 0);
            __syncthreads();
        }
    }
#pragma unroll
    for (int mi = 0; mi < 4; ++mi)
#pragma unroll
        for (int ni = 0; ni < 4; ++ni)
#pragma unroll
            for (int r = 0; r < 4; ++r) {
                const int gi = i0 + wm * 64 + mi * 16 + fq * 4 + r;
                const int gj = j0 + wn * 64 + ni * 16 + fm;
                atomicAdd(&G[(size_t)gi * Cc + gj], acc[mi][ni][r]);
            }
}

// ---------------------------------------------------------------------------
// K3a: trace(Sigma) -> rTr, sqrt(rTr).  (diagonal lives in computed tiles)
// ---------------------------------------------------------------------------
__global__ __launch_bounds__(256) void trace_kernel(const float* __restrict__ G,
                                                    const float* __restrict__ mean,
                                                    float* __restrict__ scal) {
    const int t = threadIdx.x;
    float s = 0.f;
    for (int i = t; i < Cc; i += 256)
        s += G[(size_t)i * Cc + i] * (1.0f / Mm) - mean[i] * mean[i];
    __shared__ float red[256];
    red[t] = s;
    __syncthreads();
    for (int o = 128; o > 0; o >>= 1) {
        if (t < o) red[t] += red[t + o];
        __syncthreads();
    }
    if (t == 0) {
        const float tr  = red[0] + (float)Cc * EPSC;
        const float rtr = 1.0f / tr;
        scal[0] = rtr;
        scal[1] = sqrtf(rtr);
    }
}

// ---------------------------------------------------------------------------
// K3b: Sigma_N (fp32, mirrored G read) ; P = I (fp32).
// ---------------------------------------------------------------------------
__global__ __launch_bounds__(256) void sigman_kernel(const float* __restrict__ G,
                                                     const float* __restrict__ mean,
                                                     const float* __restrict__ scal,
                                                     float* __restrict__ S,
                                                     float* __restrict__ P) {
    const int e = blockIdx.x * 256 + threadIdx.x;
    const int i = e >> 9, j = e & 511;
    const float rtr = scal[0];
    const float g = (i <= j) ? G[(size_t)i * Cc + j] : G[(size_t)j * Cc + i];
    float sig = g * (1.0f / Mm) - mean[i] * mean[j];
    if (i == j) sig += EPSC;
    S[e] = sig * rtr;
    P[e] = (i == j) ? 1.f : 0.f;
}

// ---------------------------------------------------------------------------
// K4: 512x512x512 fp32 matmul (NS chain):  C = alpha*(A@B) + beta*D.
// ---------------------------------------------------------------------------
__global__ __launch_bounds__(256) void mm512_kernel(const float* __restrict__ A,
                                                    const float* __restrict__ B,
                                                    float* __restrict__ C,
                                                    float alpha,
                                                    const float* __restrict__ D,
                                                    float beta) {
    const int ti = blockIdx.x >> 3, tj = blockIdx.x & 7;
    const int i0 = ti << 6, j0 = tj << 6;
    const int t  = threadIdx.x;
    const int tx = t & 15, ty = t >> 4;

    __shared__ float As[64][33];
    __shared__ float Bs[32][65];

    float acc[4][4] = {};

    const int lcA = t & 31, lrA = t >> 5;
    const int lcB = t & 63, lrB = t >> 6;

    for (int k0 = 0; k0 < 512; k0 += 32) {
#pragma unroll
        for (int r = 0; r < 8; ++r) {
            const int row = lrA + (r << 3);
            As[row][lcA] = A[(size_t)(i0 + row) * 512 + k0 + lcA];
        }
#pragma unroll
        for (int r = 0; r < 8; ++r) {
            const int row = lrB + (r << 2);
            Bs[row][lcB] = B[(size_t)(k0 + row) * 512 + j0 + lcB];
        }
        __syncthreads();
#pragma unroll
        for (int k = 0; k < 32; ++k) {
            float a[4], b[4];
#pragma unroll
            for (int r = 0; r < 4; ++r) a[r] = As[(ty << 2) + r][k];
#pragma unroll
            for (int cn = 0; cn < 4; ++cn) b[cn] = Bs[k][(tx << 2) + cn];
#pragma unroll
            for (int r = 0; r < 4; ++r)
#pragma unroll
                for (int cn = 0; cn < 4; ++cn) acc[r][cn] += a[r] * b[cn];
        }
        __syncthreads();
    }

#pragma unroll
    for (int r = 0; r < 4; ++r) {
        const size_t idx = (size_t)(i0 + (ty << 2) + r) * 512 + j0 + (tx << 2);
        float4 v;
        v.x = alpha * acc[r][0];
        v.y = alpha * acc[r][1];
        v.z = alpha * acc[r][2];
        v.w = alpha * acc[r][3];
        if (D) {
            const float4 d = *(const float4*)(D + idx);
            v.x += beta * d.x; v.y += beta * d.y; v.z += beta * d.z; v.w += beta * d.w;
        }
        *(float4*)(C + idx) = v;
    }
}

// ---------------------------------------------------------------------------
// K5: wmm[c] = sqrt(rTr) * sum_j P[c][j]*mean[j]   (fp32 P)
// ---------------------------------------------------------------------------
__global__ __launch_bounds__(128) void wmm_kernel(const float* __restrict__ P,
                                                  const float* __restrict__ mean,
                                                  const float* __restrict__ scal,
                                                  float* __restrict__ wmm) {
    const int c = blockIdx.x, t = threadIdx.x;
    float s = 0.f;
    for (int j = t; j < Cc; j += 128) s += P[(size_t)c * Cc + j] * mean[j];
    __shared__ float red[128];
    red[t] = s;
    __syncthreads();
    for (int o = 64; o > 0; o >>= 1) {
        if (t < o) red[t] += red[t + o];
        __syncthreads();
    }
    if (t == 0) wmm[c] = red[0] * scal[1];
}

// ---------------------------------------------------------------------------
// K5b: final P fp32 -> bf16
// ---------------------------------------------------------------------------
__global__ __launch_bounds__(256) void p2bf_kernel(const float* __restrict__ P,
                                                   u16* __restrict__ Pbf) {
    const int e = (blockIdx.x * 256 + threadIdx.x) << 2;
    float4 v = *(const float4*)&P[e];
    *(ushort4*)&Pbf[e] = make_ushort4(f2bf(v.x), f2bf(v.y), f2bf(v.z), f2bf(v.w));
}

// ---------------------------------------------------------------------------
// K6: whiten via bf16 MFMA.  D[s][c'] = sum_c Xt[s][c]*Pbf[c'][c];
// out[n][c'][s] = sr*D - wmm[c'].  Grid (4 c'-tiles, 8 hw-tiles, 64 n).
// ---------------------------------------------------------------------------
__global__ __launch_bounds__(256) void whiten_mfma(const u16* __restrict__ Xt,
                                                   const u16* __restrict__ Pbf,
                                                   const float* __restrict__ wmm,
                                                   const float* __restrict__ scal,
                                                   float* __restrict__ out) {
    const int c0 = blockIdx.x << 7;   // c' tile
    const int h0 = blockIdx.y << 7;   // hw (s) tile
    const int n  = blockIdx.z;
    const int t  = threadIdx.x;
    const int w  = t >> 6, l = t & 63;

    __shared__ u16 As[128 * 32];      // Xt rows (s-major, k=c contiguous)
    __shared__ u16 Bs[128 * 32];      // P rows  (c'-major, k=c contiguous)

    floatx4 acc[4][4];
#pragma unroll
    for (int mi = 0; mi < 4; ++mi)
#pragma unroll
        for (int ni = 0; ni < 4; ++ni) acc[mi][ni] = (floatx4){0.f, 0.f, 0.f, 0.f};

    const int lr = l >> 2;
    const int lc = (l & 3) << 3;
    const int wm = w >> 1, wn = w & 1;
    const int fm = l & 15, fq = l >> 4;

    const u16* Xn = Xt + (size_t)n * CHW;

    for (int kk = 0; kk < Cc; kk += 32) {
#pragma unroll
        for (int p = 0; p < 2; ++p) {
            const int g   = w * 2 + p;
            const int row = g * 16 + lr;
            gld_lds16(Xn  + (size_t)(h0 + row) * Cc + kk + lc, &As[g * 512]);
            gld_lds16(Pbf + (size_t)(c0 + row) * Cc + kk + lc, &Bs[g * 512]);
        }
        __syncthreads();
        short8 a[4], b[4];
#pragma unroll
        for (int mi = 0; mi < 4; ++mi)
            a[mi] = *(const short8*)&As[(wm * 64 + mi * 16 + fm) * 32 + fq * 8];
#pragma unroll
        for (int ni = 0; ni < 4; ++ni)
            b[ni] = *(const short8*)&Bs[(wn * 64 + ni * 16 + fm) * 32 + fq * 8];
#pragma unroll
        for (int mi = 0; mi < 4; ++mi)
#pragma unroll
            for (int ni = 0; ni < 4; ++ni)
                acc[mi][ni] = __builtin_amdgcn_mfma_f32_16x16x32_bf16(
                    a[mi], b[ni], acc[mi][ni], 0, 0, 0);
        __syncthreads();
    }

    const float sr = scal[1];
    float* outn = out + (size_t)n * CHW;
#pragma unroll
    for (int ni = 0; ni < 4; ++ni) {
        const int cp = c0 + wn * 64 + ni * 16 + fm;
        const float wv = wmm[cp];
#pragma unroll
        for (int mi = 0; mi < 4; ++mi) {
            const int s = h0 + wm * 64 + mi * 16 + fq * 4;
            floatx4 v = acc[mi][ni] * sr - wv;
            *(floatx4*)&outn[(size_t)cp * HWs + s] = v;
        }
    }
}

// ---------------------------------------------------------------------------
// Fallback fp32 kernels (round-1 path, used only if ws too small)
// ---------------------------------------------------------------------------
__global__ __launch_bounds__(256) void gram_kernel(const float* __restrict__ X,
                                                   float* __restrict__ G) {
    const int ti = blockIdx.x >> 3, tj = blockIdx.x & 7;
    const int i0 = ti << 6, j0 = tj << 6;
    const int n0 = blockIdx.y << 3;
    const int t  = threadIdx.x;
    const int tx = t & 15, ty = t >> 4;
    __shared__ float As[64][33];
    __shared__ float Bs[64][33];
    float acc[4][4] = {};
    const int lc = t & 31;
    const int lr0 = t >> 5;
    for (int n = n0; n < n0 + 8; ++n) {
        const float* Xn = X + (size_t)n * CHW;
        for (int hw0 = 0; hw0 < HWs; hw0 += 32) {
#pragma unroll
            for (int r = 0; r < 8; ++r) {
                const int row = lr0 + (r << 3);
                As[row][lc] = Xn[(size_t)(i0 + row) * HWs + hw0 + lc];
                Bs[row][lc] = Xn[(size_t)(j0 + row) * HWs + hw0 + lc];
            }
            __syncthreads();
#pragma unroll
            for (int k = 0; k < 32; ++k) {
                float a[4], b[4];
#pragma unroll
                for (int r = 0; r < 4; ++r) a[r] = As[(ty << 2) + r][k];
#pragma unroll
                for (int cn = 0; cn < 4; ++cn) b[cn] = Bs[(tx << 2) + cn][k];
#pragma unroll
                for (int r = 0; r < 4; ++r)
#pragma unroll
                    for (int cn = 0; cn < 4; ++cn) acc[r][cn] += a[r] * b[cn];
            }
            __syncthreads();
        }
    }
#pragma unroll
    for (int r = 0; r < 4; ++r)
#pragma unroll
        for (int cn = 0; cn < 4; ++cn)
            atomicAdd(&G[(size_t)(i0 + (ty << 2) + r) * Cc + j0 + (tx << 2) + cn],
                      acc[r][cn]);
}

__global__ __launch_bounds__(256) void whiten_kernel(const float* __restrict__ X,
                                                     const float* __restrict__ P,
                                                     const float* __restrict__ wmm,
                                                     const float* __restrict__ scal,
                                                     float* __restrict__ out) {
    const int c0 = blockIdx.x << 6;
    const int h0 = blockIdx.y << 6;
    const int n  = blockIdx.z;
    const int t  = threadIdx.x;
    const int tx = t & 15, ty = t >> 4;
    __shared__ float Ps[64][33];
    __shared__ float Xs[32][65];
    float acc[4][4] = {};
    const int lcA = t & 31, lrA = t >> 5;
    const int lcB = t & 63, lrB = t >> 6;
    const float* Xn = X + (size_t)n * CHW;
    for (int k0 = 0; k0 < 512; k0 += 32) {
#pragma unroll
        for (int r = 0; r < 8; ++r) {
            const int row = lrA + (r << 3);
            Ps[row][lcA] = P[(size_t)(c0 + row) * 512 + k0 + lcA];
        }
#pragma unroll
        for (int r = 0; r < 8; ++r) {
            const int row = lrB + (r << 2);
            Xs[row][lcB] = Xn[(size_t)(k0 + row) * HWs + h0 + lcB];
        }
        __syncthreads();
#pragma unroll
        for (int k = 0; k < 32; ++k) {
            float a[4], b[4];
#pragma unroll
            for (int r = 0; r < 4; ++r) a[r] = Ps[(ty << 2) + r][k];
#pragma unroll
            for (int cn = 0; cn < 4; ++cn) b[cn] = Xs[k][(tx << 2) + cn];
#pragma unroll
            for (int r = 0; r < 4; ++r)
#pragma unroll
                for (int cn = 0; cn < 4; ++cn) acc[r][cn] += a[r] * b[cn];
        }
        __syncthreads();
    }
    const float sr = scal[1];
#pragma unroll
    for (int r = 0; r < 4; ++r) {
        const int c = c0 + (ty << 2) + r;
        const float wv = wmm[c];
        float4 v;
        v.x = sr * acc[r][0] - wv;
        v.y = sr * acc[r][1] - wv;
        v.z = sr * acc[r][2] - wv;
        v.w = sr * acc[r][3] - wv;
        *(float4*)(out + (size_t)n * CHW + (size_t)c * HWs + h0 + (tx << 2)) = v;
    }
}

__global__ __launch_bounds__(256) void sigman_full_kernel(const float* __restrict__ G,
                                                          const float* __restrict__ mean,
                                                          const float* __restrict__ scal,
                                                          float* __restrict__ S,
                                                          float* __restrict__ P) {
    const int e = blockIdx.x * 256 + threadIdx.x;
    const int i = e >> 9, j = e & 511;
    const float rtr = scal[0];
    float sig = G[e] * (1.0f / Mm) - mean[i] * mean[j];
    if (i == j) sig += EPSC;
    S[e] = sig * rtr;
    P[e] = (i == j) ? 1.f : 0.f;
}

// ---------------------------------------------------------------------------
extern "C" void kernel_launch(void* const* d_in, const int* in_sizes, int n_in,
                              void* d_out, int out_size, void* d_ws, size_t ws_size,
                              hipStream_t stream) {
    const float* X = (const float*)d_in[0];
    float* out     = (float*)d_out;

    // fast-path workspace: Xbf(64MB bf16) + Xt(64MB bf16) + Pbf + fp32 matrices
    const size_t NEED = (size_t)CHW * Nn * 2 * 2    // Xbf + Xt
                      + (size_t)262144 * 2          // Pbf
                      + (size_t)(2048 + 6 * 262144) * 4;

    if (ws_size >= NEED) {
        u16* Xbf = (u16*)d_ws;
        u16* Xt  = Xbf + (size_t)CHW * Nn;
        u16* Pbf = Xt  + (size_t)CHW * Nn;
        float* f    = (float*)(Pbf + 262144);
        float* mean = f;
        float* wmm  = f + 512;
        float* scal = f + 1024;
        float* G    = f + 2048;
        float* S    = G + 262144;
        float* Pa   = S + 262144;
        float* Pb   = Pa + 262144;
        float* P2   = Pb + 262144;
        float* P3   = P2 + 262144;

        mean_kernel<<<512, 256, 0, stream>>>(X, mean);
        convert_transpose<<<dim3(16, 8, 64), 256, 0, stream>>>(X, Xbf, Xt);
        hipMemsetAsync(G, 0, sizeof(float) * 262144, stream);
        gram_mfma<<<dim3(10, 32), 256, 0, stream>>>(Xbf, G);
        trace_kernel<<<1, 256, 0, stream>>>(G, mean, scal);
        sigman_kernel<<<1024, 256, 0, stream>>>(G, mean, scal, S, Pa);

        float* P  = Pa;
        float* Pn = Pb;
        for (int it = 0; it < 5; ++it) {
            mm512_kernel<<<64, 256, 0, stream>>>(P, P, P2, 1.f, nullptr, 0.f);
            mm512_kernel<<<64, 256, 0, stream>>>(P2, P, P3, 1.f, nullptr, 0.f);
            mm512_kernel<<<64, 256, 0, stream>>>(P3, S, Pn, -0.5f, P, 1.5f);
            float* tmp = P; P = Pn; Pn = tmp;
        }

        p2bf_kernel<<<256, 256, 0, stream>>>(P, Pbf);
        wmm_kernel<<<512, 128, 0, stream>>>(P, mean, scal, wmm);
        whiten_mfma<<<dim3(4, 8, 64), 256, 0, stream>>>(Xt, Pbf, wmm, scal, out);
    } else {
        // fallback: round-1 fp32 path (~6.3 MB ws)
        float* ws   = (float*)d_ws;
        float* mean = ws;
        float* wmm  = ws + 512;
        float* scal = ws + 1024;
        float* G    = ws + 2048;
        float* S    = G + 262144;
        float* Pa   = S + 262144;
        float* Pb   = Pa + 262144;
        float* P2   = Pb + 262144;
        float* P3   = P2 + 262144;

        mean_kernel<<<512, 256, 0, stream>>>(X, mean);
        hipMemsetAsync(G, 0, sizeof(float) * 262144, stream);
        gram_kernel<<<dim3(64, 8), 256, 0, stream>>>(X, G);
        trace_kernel<<<1, 256, 0, stream>>>(G, mean, scal);
        sigman_full_kernel<<<1024, 256, 0, stream>>>(G, mean, scal, S, Pa);

        float* P  = Pa;
        float* Pn = Pb;
        for (int it = 0; it < 5; ++it) {
            mm512_kernel<<<64, 256, 0, stream>>>(P, P, P2, 1.f, nullptr, 0.f);
            mm512_kernel<<<64, 256, 0, stream>>>(P2, P, P3, 1.f, nullptr, 0.f);
            mm512_kernel<<<64, 256, 0, stream>>>(P3, S, Pn, -0.5f, P, 1.5f);
            float* tmp = P; P = Pn; Pn = tmp;
        }

        wmm_kernel<<<512, 128, 0, stream>>>(P, mean, scal, wmm);
        whiten_kernel<<<dim3(8, 16, 64), 256, 0, stream>>>(X, P, wmm, scal, out);
    }
}

// Round 3
// 546.553 us; speedup vs baseline: 3.8410x; 1.5809x over previous
//
#include <hip/hip_runtime.h>
#include <math.h>

// Problem constants (X: [64, 512, 32, 32] fp32)
#define Nn   64
#define Cc   512
#define HWs  1024
#define CHW  (Cc * HWs)      // 524288
#define Mm   (Nn * HWs)      // 65536
#define EPSC 1e-5f

typedef unsigned int   u32;
typedef unsigned short u16;
typedef __attribute__((ext_vector_type(8))) short  short8;   // 8 x bf16 = 4 VGPR
typedef __attribute__((ext_vector_type(4))) float  floatx4;

__device__ __forceinline__ u16 f2bf(float f) {
    u32 u = __float_as_uint(f);
    u += 0x7fff + ((u >> 16) & 1);   // RNE
    return (u16)(u >> 16);
}
__device__ __forceinline__ float bf2f(u16 h) {
    return __uint_as_float(((u32)h) << 16);
}

__device__ __forceinline__ void gld_lds16(const u16* g, u16* l) {
    // async global->LDS, 16B per lane; LDS dest = wave-uniform base + lane*16
    __builtin_amdgcn_global_load_lds(
        (const __attribute__((address_space(1))) u32*)g,
        (__attribute__((address_space(3))) u32*)l, 16, 0, 0);
}

// ---------------------------------------------------------------------------
// K0: fp32 -> bf16 convert (natural layout) + transposed copy Xt[n][hw][c]
//     + fused per-channel partial sums into meanP[16][512] (atomics).
// Grid (16 hw-tiles, 8 c-tiles, 64 n), 256 threads.
// ---------------------------------------------------------------------------
__global__ __launch_bounds__(256) void convert_transpose(const float* __restrict__ X,
                                                         u16* __restrict__ Xbf,
                                                         u16* __restrict__ Xt,
                                                         float* __restrict__ meanP) {
    const int hT = blockIdx.x;
    const int h0 = hT << 6;
    const int c0 = blockIdx.y << 6;
    const int n  = blockIdx.z;
    const int t  = threadIdx.x;
    __shared__ u16   T[64][65];
    __shared__ float red[64][17];

    const float* Xn  = X   + (size_t)n * CHW;
    u16*         Xbn = Xbf + (size_t)n * CHW;
    u16*         Xtn = Xt  + (size_t)n * CHW;

    const int cl = t >> 4;          // 0..15
    const int h4 = (t & 15) << 2;   // 0,4,..,60
#pragma unroll
    for (int i = 0; i < 4; ++i) {
        const int c = cl + (i << 4);
        float4 v = *(const float4*)&Xn[(size_t)(c0 + c) * HWs + h0 + h4];
        red[c][t & 15] = v.x + v.y + v.z + v.w;
        u16 b0 = f2bf(v.x), b1 = f2bf(v.y), b2 = f2bf(v.z), b3 = f2bf(v.w);
        *(ushort4*)&Xbn[(size_t)(c0 + c) * HWs + h0 + h4] = make_ushort4(b0, b1, b2, b3);
        T[c][h4]     = b0;
        T[c][h4 + 1] = b1;
        T[c][h4 + 2] = b2;
        T[c][h4 + 3] = b3;
    }
    __syncthreads();
    const int hl = t >> 4;
    const int c4 = (t & 15) << 2;
#pragma unroll
    for (int i = 0; i < 4; ++i) {
        const int h = hl + (i << 4);
        ushort4 pk = make_ushort4(T[c4][h], T[c4 + 1][h], T[c4 + 2][h], T[c4 + 3][h]);
        *(ushort4*)&Xtn[(size_t)(h0 + h) * Cc + c0 + c4] = pk;
    }
    if (t < 64) {
        float s = 0.f;
#pragma unroll
        for (int j = 0; j < 16; ++j) s += red[t][j];
        atomicAdd(&meanP[hT * 512 + c0 + t], s);
    }
}

// ---------------------------------------------------------------------------
// K2: Gram via bf16 MFMA, upper-triangle 128x128 tiles, split-K over n-pairs.
// 1D grid 320 with XCD-co-locating swizzle (10 tile-blocks of one n-split
// share ids mod 8 -> same XCD -> shared L2 for the X slices).
// ---------------------------------------------------------------------------
__global__ __launch_bounds__(256) void gram_mfma(const u16* __restrict__ Xbf,
                                                 float* __restrict__ G) {
    static const int TI[10] = {0,0,0,0,1,1,1,2,2,3};
    static const int TJ[10] = {0,1,2,3,1,2,3,2,3,3};
    const int id = blockIdx.x;
    const int q  = id >> 3;
    const int x  = q % 10;                        // tile index
    const int y  = (id & 7) + ((q / 10) << 3);    // n-split 0..31
    const int i0 = TI[x] << 7;
    const int j0 = TJ[x] << 7;
    const int n0 = y << 1;
    const int t  = threadIdx.x;
    const int w  = t >> 6, l = t & 63;

    __shared__ u16 As[128 * 32];
    __shared__ u16 Bs[128 * 32];

    floatx4 acc[4][4];
#pragma unroll
    for (int mi = 0; mi < 4; ++mi)
#pragma unroll
        for (int ni = 0; ni < 4; ++ni) acc[mi][ni] = (floatx4){0.f, 0.f, 0.f, 0.f};

    const int lr = l >> 2;
    const int lc = (l & 3) << 3;
    const int wm = w >> 1, wn = w & 1;
    const int fm = l & 15, fq = l >> 4;

    for (int n = n0; n < n0 + 2; ++n) {
        const u16* Xn = Xbf + (size_t)n * CHW;
        for (int hw = 0; hw < HWs; hw += 32) {
#pragma unroll
            for (int p = 0; p < 2; ++p) {
                const int g   = w * 2 + p;
                const int row = g * 16 + lr;
                gld_lds16(Xn + (size_t)(i0 + row) * HWs + hw + lc, &As[g * 512]);
                gld_lds16(Xn + (size_t)(j0 + row) * HWs + hw + lc, &Bs[g * 512]);
            }
            __syncthreads();
            short8 a[4], b[4];
#pragma unroll
            for (int mi = 0; mi < 4; ++mi)
                a[mi] = *(const short8*)&As[(wm * 64 + mi * 16 + fm) * 32 + fq * 8];
#pragma unroll
            for (int ni = 0; ni < 4; ++ni)
                b[ni] = *(const short8*)&Bs[(wn * 64 + ni * 16 + fm) * 32 + fq * 8];
#pragma unroll
            for (int mi = 0; mi < 4; ++mi)
#pragma unroll
                for (int ni = 0; ni < 4; ++ni)
                    acc[mi][ni] = __builtin_amdgcn_mfma_f32_16x16x32_bf16(
                        a[mi], b[ni], acc[mi][ni], 0, 0, 0);
            __syncthreads();
        }
    }
#pragma unroll
    for (int mi = 0; mi < 4; ++mi)
#pragma unroll
        for (int ni = 0; ni < 4; ++ni)
#pragma unroll
            for (int r = 0; r < 4; ++r) {
                const int gi = i0 + wm * 64 + mi * 16 + fq * 4 + r;
                const int gj = j0 + wn * 64 + ni * 16 + fm;
                atomicAdd(&G[(size_t)gi * Cc + gj], acc[mi][ni][r]);
            }
}

// ---------------------------------------------------------------------------
// K3a: reduce meanP -> mean; trace(Sigma) -> rTr, sqrt(rTr).  One block.
// ---------------------------------------------------------------------------
__global__ __launch_bounds__(256) void trace_kernel(const float* __restrict__ G,
                                                    const float* __restrict__ meanP,
                                                    float* __restrict__ mean,
                                                    float* __restrict__ scal) {
    const int t = threadIdx.x;
    for (int c = t; c < Cc; c += 256) {
        float s = 0.f;
#pragma unroll
        for (int j = 0; j < 16; ++j) s += meanP[j * 512 + c];
        mean[c] = s * (1.0f / Mm);
    }
    __syncthreads();
    float s = 0.f;
    for (int i = t; i < Cc; i += 256)
        s += G[(size_t)i * Cc + i] * (1.0f / Mm) - mean[i] * mean[i];
    __shared__ float red[256];
    red[t] = s;
    __syncthreads();
    for (int o = 128; o > 0; o >>= 1) {
        if (t < o) red[t] += red[t + o];
        __syncthreads();
    }
    if (t == 0) {
        const float tr  = red[0] + (float)Cc * EPSC;
        const float rtr = 1.0f / tr;
        scal[0] = rtr;
        scal[1] = sqrtf(rtr);
    }
}

// ---------------------------------------------------------------------------
// K3b: Sigma_N as split-bf16 (Sh/Sl); P0 = I as fp32 + split-bf16.
// ---------------------------------------------------------------------------
__global__ __launch_bounds__(256) void sigman_kernel(const float* __restrict__ G,
                                                     const float* __restrict__ mean,
                                                     const float* __restrict__ scal,
                                                     u16* __restrict__ Sh,
                                                     u16* __restrict__ Sl,
                                                     float* __restrict__ Pf,
                                                     u16* __restrict__ Ph,
                                                     u16* __restrict__ Pl) {
    const int e = blockIdx.x * 256 + threadIdx.x;
    const int i = e >> 9, j = e & 511;
    const float rtr = scal[0];
    const float g = (i <= j) ? G[(size_t)i * Cc + j] : G[(size_t)j * Cc + i];
    float sig = g * (1.0f / Mm) - mean[i] * mean[j];
    if (i == j) sig += EPSC;
    const float sN = sig * rtr;
    const u16 h = f2bf(sN);
    Sh[e] = h;
    Sl[e] = f2bf(sN - bf2f(h));
    const float pv = (i == j) ? 1.f : 0.f;
    Pf[e] = pv;
    Ph[e] = (i == j) ? (u16)0x3F80 : (u16)0;
    Pl[e] = 0;
}

// ---------------------------------------------------------------------------
// K4: 512x512x512 split-bf16 MFMA matmul for the NS chain.
// Computes D[i][j] = sum_k A[i][k]*B[j][k]  (= A@B since all operands are
// symmetric).  C = alpha*(A@B) + beta*D, emitted as fp32 (optional) + hi/lo
// bf16.  64 blocks of 64x64 tiles, 4 waves (2x2 of 32x32), BK=32.
// ---------------------------------------------------------------------------
__global__ __launch_bounds__(256) void mm512s(const u16* __restrict__ Ah,
                                              const u16* __restrict__ Al,
                                              const u16* __restrict__ Bh,
                                              const u16* __restrict__ Bl,
                                              float alpha,
                                              const float* __restrict__ D,
                                              float beta,
                                              float* __restrict__ Cf,
                                              u16* __restrict__ Ch,
                                              u16* __restrict__ Cl) {
    const int i0 = (blockIdx.x >> 3) << 6;
    const int j0 = (blockIdx.x & 7) << 6;
    const int t  = threadIdx.x;
    const int w  = t >> 6, l = t & 63;
    const int wm = w >> 1, wn = w & 1;
    const int fm = l & 15, fq = l >> 4;
    const int lr = l >> 2, lc = (l & 3) << 3;

    __shared__ u16 S4[4][64 * 32];   // Ah, Al, Bh, Bl tiles

    const u16* src;
    int rbase;
    if (w == 0)      { src = Ah; rbase = i0; }
    else if (w == 1) { src = Al; rbase = i0; }
    else if (w == 2) { src = Bh; rbase = j0; }
    else             { src = Bl; rbase = j0; }

    floatx4 acc[2][2];
#pragma unroll
    for (int mi = 0; mi < 2; ++mi)
#pragma unroll
        for (int ni = 0; ni < 2; ++ni) acc[mi][ni] = (floatx4){0.f, 0.f, 0.f, 0.f};

    for (int k0 = 0; k0 < 512; k0 += 32) {
#pragma unroll
        for (int g = 0; g < 4; ++g)
            gld_lds16(src + (size_t)(rbase + g * 16 + lr) * 512 + k0 + lc,
                      &S4[w][g * 512]);
        __syncthreads();
        short8 ah[2], al[2], bh[2], bl[2];
#pragma unroll
        for (int mi = 0; mi < 2; ++mi) {
            const int ro = (wm * 32 + mi * 16 + fm) * 32 + fq * 8;
            ah[mi] = *(const short8*)&S4[0][ro];
            al[mi] = *(const short8*)&S4[1][ro];
        }
#pragma unroll
        for (int ni = 0; ni < 2; ++ni) {
            const int ro = (wn * 32 + ni * 16 + fm) * 32 + fq * 8;
            bh[ni] = *(const short8*)&S4[2][ro];
            bl[ni] = *(const short8*)&S4[3][ro];
        }
#pragma unroll
        for (int mi = 0; mi < 2; ++mi)
#pragma unroll
            for (int ni = 0; ni < 2; ++ni) {
                acc[mi][ni] = __builtin_amdgcn_mfma_f32_16x16x32_bf16(ah[mi], bh[ni], acc[mi][ni], 0, 0, 0);
                acc[mi][ni] = __builtin_amdgcn_mfma_f32_16x16x32_bf16(ah[mi], bl[ni], acc[mi][ni], 0, 0, 0);
                acc[mi][ni] = __builtin_amdgcn_mfma_f32_16x16x32_bf16(al[mi], bh[ni], acc[mi][ni], 0, 0, 0);
            }
        __syncthreads();
    }

#pragma unroll
    for (int mi = 0; mi < 2; ++mi)
#pragma unroll
        for (int ni = 0; ni < 2; ++ni)
#pragma unroll
            for (int r = 0; r < 4; ++r) {
                const int gi = i0 + wm * 32 + mi * 16 + fq * 4 + r;
                const int gj = j0 + wn * 32 + ni * 16 + fm;
                const size_t idx = (size_t)gi * 512 + gj;
                float v = alpha * acc[mi][ni][r];
                if (D) v += beta * D[idx];
                if (Cf) Cf[idx] = v;
                const u16 h = f2bf(v);
                Ch[idx] = h;
                Cl[idx] = f2bf(v - bf2f(h));
            }
}

// ---------------------------------------------------------------------------
// K5: wmm[c] = sqrt(rTr) * sum_j P[c][j]*mean[j]   (fp32 P)
// ---------------------------------------------------------------------------
__global__ __launch_bounds__(128) void wmm_kernel(const float* __restrict__ P,
                                                  const float* __restrict__ mean,
                                                  const float* __restrict__ scal,
                                                  float* __restrict__ wmm) {
    const int c = blockIdx.x, t = threadIdx.x;
    float s = 0.f;
    for (int j = t; j < Cc; j += 128) s += P[(size_t)c * Cc + j] * mean[j];
    __shared__ float red[128];
    red[t] = s;
    __syncthreads();
    for (int o = 64; o > 0; o >>= 1) {
        if (t < o) red[t] += red[t + o];
        __syncthreads();
    }
    if (t == 0) wmm[c] = red[0] * scal[1];
}

// ---------------------------------------------------------------------------
// K6: whiten via bf16 MFMA.  1D grid 2048 with XCD swizzle (4 c'-tile blocks
// sharing an Xt slice -> same XCD).  LDS-staged epilogue: full-line stores.
// ---------------------------------------------------------------------------
__global__ __launch_bounds__(256) void whiten_mfma(const u16* __restrict__ Xt,
                                                   const u16* __restrict__ Pbf,
                                                   const float* __restrict__ wmm,
                                                   const float* __restrict__ scal,
                                                   float* __restrict__ out) {
    const int id  = blockIdx.x;
    const int m   = (id >> 3) & 3;                 // c'-tile (member)
    const int grp = (id & 7) + ((id >> 5) << 3);   // 0..511
    const int c0  = m << 7;
    const int h0  = (grp & 7) << 7;
    const int n   = grp >> 3;
    const int t   = threadIdx.x;
    const int w   = t >> 6, l = t & 63;

    __shared__ char smem[128 * 68 * 4];            // 34816 B (>= 16 KB staging)
    u16* As = (u16*)smem;                          // 128x32
    u16* Bs = As + 4096;                           // 128x32
    float* Ep = (float*)smem;                      // epilogue tile [128][68]

    floatx4 acc[4][4];
#pragma unroll
    for (int mi = 0; mi < 4; ++mi)
#pragma unroll
        for (int ni = 0; ni < 4; ++ni) acc[mi][ni] = (floatx4){0.f, 0.f, 0.f, 0.f};

    const int lr = l >> 2;
    const int lc = (l & 3) << 3;
    const int wm = w >> 1, wn = w & 1;
    const int fm = l & 15, fq = l >> 4;

    const u16* Xn = Xt + (size_t)n * CHW;

    for (int kk = 0; kk < Cc; kk += 32) {
#pragma unroll
        for (int p = 0; p < 2; ++p) {
            const int g   = w * 2 + p;
            const int row = g * 16 + lr;
            gld_lds16(Xn  + (size_t)(h0 + row) * Cc + kk + lc, &As[g * 512]);
            gld_lds16(Pbf + (size_t)(c0 + row) * Cc + kk + lc, &Bs[g * 512]);
        }
        __syncthreads();
        short8 a[4], b[4];
#pragma unroll
        for (int mi = 0; mi < 4; ++mi)
            a[mi] = *(const short8*)&As[(wm * 64 + mi * 16 + fm) * 32 + fq * 8];
#pragma unroll
        for (int ni = 0; ni < 4; ++ni)
            b[ni] = *(const short8*)&Bs[(wn * 64 + ni * 16 + fm) * 32 + fq * 8];
#pragma unroll
        for (int mi = 0; mi < 4; ++mi)
#pragma unroll
            for (int ni = 0; ni < 4; ++ni)
                acc[mi][ni] = __builtin_amdgcn_mfma_f32_16x16x32_bf16(
                    a[mi], b[ni], acc[mi][ni], 0, 0, 0);
        __syncthreads();
    }

    const float sr = scal[1];
    float wv[4];
#pragma unroll
    for (int ni = 0; ni < 4; ++ni) wv[ni] = wmm[c0 + wn * 64 + ni * 16 + fm];
    float* outn = out + (size_t)n * CHW;

    // Epilogue: 2 rounds of mi-pairs; each round stages [128 c'][64 s] in LDS
    // (stride 68 -> conflict-free), then stores 256B-contiguous row segments.
#pragma unroll
    for (int mp = 0; mp < 2; ++mp) {
        __syncthreads();
#pragma unroll
        for (int p = 0; p < 2; ++p) {
            const int mi = mp * 2 + p;
#pragma unroll
            for (int ni = 0; ni < 4; ++ni) {
                const int row  = wn * 64 + ni * 16 + fm;
                const int slot = wm * 32 + p * 16 + fq * 4;
                floatx4 v = acc[mi][ni] * sr - wv[ni];
                *(floatx4*)&Ep[row * 68 + slot] = v;
            }
        }
        __syncthreads();
#pragma unroll
        for (int jj = 0; jj < 8; ++jj) {
            const int idx = jj * 256 + t;          // 2048 float4
            const int row = idx >> 4;
            const int s4  = (idx & 15) << 2;       // 0..60
            const int wmr = s4 >> 5;
            const int within = s4 & 31;
            float4 v = *(const float4*)&Ep[row * 68 + s4];
            *(float4*)&outn[(size_t)(c0 + row) * HWs + h0 + wmr * 64 + mp * 32 + within] = v;
        }
    }
}

// ---------------------------------------------------------------------------
// Fallback fp32 kernels (round-1 path, used only if ws too small)
// ---------------------------------------------------------------------------
__global__ __launch_bounds__(256) void mean_kernel(const float* __restrict__ X,
                                                   float* __restrict__ mean) {
    const int c = blockIdx.x;
    const int t = threadIdx.x;
    float s = 0.f;
    for (int n = 0; n < Nn; ++n) {
        const float4* p = (const float4*)(X + (size_t)n * CHW + (size_t)c * HWs);
        float4 v = p[t];
        s += v.x + v.y + v.z + v.w;
    }
    __shared__ float red[256];
    red[t] = s;
    __syncthreads();
    for (int o = 128; o > 0; o >>= 1) {
        if (t < o) red[t] += red[t + o];
        __syncthreads();
    }
    if (t == 0) mean[c] = red[0] * (1.0f / Mm);
}

__global__ __launch_bounds__(256) void trace_fb(const float* __restrict__ G,
                                                const float* __restrict__ mean,
                                                float* __restrict__ scal) {
    const int t = threadIdx.x;
    float s = 0.f;
    for (int i = t; i < Cc; i += 256)
        s += G[(size_t)i * Cc + i] * (1.0f / Mm) - mean[i] * mean[i];
    __shared__ float red[256];
    red[t] = s;
    __syncthreads();
    for (int o = 128; o > 0; o >>= 1) {
        if (t < o) red[t] += red[t + o];
        __syncthreads();
    }
    if (t == 0) {
        const float tr  = red[0] + (float)Cc * EPSC;
        const float rtr = 1.0f / tr;
        scal[0] = rtr;
        scal[1] = sqrtf(rtr);
    }
}

__global__ __launch_bounds__(256) void gram_kernel(const float* __restrict__ X,
                                                   float* __restrict__ G) {
    const int ti = blockIdx.x >> 3, tj = blockIdx.x & 7;
    const int i0 = ti << 6, j0 = tj << 6;
    const int n0 = blockIdx.y << 3;
    const int t  = threadIdx.x;
    const int tx = t & 15, ty = t >> 4;
    __shared__ float As[64][33];
    __shared__ float Bs[64][33];
    float acc[4][4] = {};
    const int lc = t & 31;
    const int lr0 = t >> 5;
    for (int n = n0; n < n0 + 8; ++n) {
        const float* Xn = X + (size_t)n * CHW;
        for (int hw0 = 0; hw0 < HWs; hw0 += 32) {
#pragma unroll
            for (int r = 0; r < 8; ++r) {
                const int row = lr0 + (r << 3);
                As[row][lc] = Xn[(size_t)(i0 + row) * HWs + hw0 + lc];
                Bs[row][lc] = Xn[(size_t)(j0 + row) * HWs + hw0 + lc];
            }
            __syncthreads();
#pragma unroll
            for (int k = 0; k < 32; ++k) {
                float a[4], b[4];
#pragma unroll
                for (int r = 0; r < 4; ++r) a[r] = As[(ty << 2) + r][k];
#pragma unroll
                for (int cn = 0; cn < 4; ++cn) b[cn] = Bs[(tx << 2) + cn][k];
#pragma unroll
                for (int r = 0; r < 4; ++r)
#pragma unroll
                    for (int cn = 0; cn < 4; ++cn) acc[r][cn] += a[r] * b[cn];
            }
            __syncthreads();
        }
    }
#pragma unroll
    for (int r = 0; r < 4; ++r)
#pragma unroll
        for (int cn = 0; cn < 4; ++cn)
            atomicAdd(&G[(size_t)(i0 + (ty << 2) + r) * Cc + j0 + (tx << 2) + cn],
                      acc[r][cn]);
}

__global__ __launch_bounds__(256) void sigman_full_kernel(const float* __restrict__ G,
                                                          const float* __restrict__ mean,
                                                          const float* __restrict__ scal,
                                                          float* __restrict__ S,
                                                          float* __restrict__ P) {
    const int e = blockIdx.x * 256 + threadIdx.x;
    const int i = e >> 9, j = e & 511;
    const float rtr = scal[0];
    float sig = G[e] * (1.0f / Mm) - mean[i] * mean[j];
    if (i == j) sig += EPSC;
    S[e] = sig * rtr;
    P[e] = (i == j) ? 1.f : 0.f;
}

__global__ __launch_bounds__(256) void mm512_kernel(const float* __restrict__ A,
                                                    const float* __restrict__ B,
                                                    float* __restrict__ C,
                                                    float alpha,
                                                    const float* __restrict__ D,
                                                    float beta) {
    const int ti = blockIdx.x >> 3, tj = blockIdx.x & 7;
    const int i0 = ti << 6, j0 = tj << 6;
    const int t  = threadIdx.x;
    const int tx = t & 15, ty = t >> 4;
    __shared__ float As[64][33];
    __shared__ float Bs[32][65];
    float acc[4][4] = {};
    const int lcA = t & 31, lrA = t >> 5;
    const int lcB = t & 63, lrB = t >> 6;
    for (int k0 = 0; k0 < 512; k0 += 32) {
#pragma unroll
        for (int r = 0; r < 8; ++r) {
            const int row = lrA + (r << 3);
            As[row][lcA] = A[(size_t)(i0 + row) * 512 + k0 + lcA];
        }
#pragma unroll
        for (int r = 0; r < 8; ++r) {
            const int row = lrB + (r << 2);
            Bs[row][lcB] = B[(size_t)(k0 + row) * 512 + j0 + lcB];
        }
        __syncthreads();
#pragma unroll
        for (int k = 0; k < 32; ++k) {
            float a[4], b[4];
#pragma unroll
            for (int r = 0; r < 4; ++r) a[r] = As[(ty << 2) + r][k];
#pragma unroll
            for (int cn = 0; cn < 4; ++cn) b[cn] = Bs[k][(tx << 2) + cn];
#pragma unroll
            for (int r = 0; r < 4; ++r)
#pragma unroll
                for (int cn = 0; cn < 4; ++cn) acc[r][cn] += a[r] * b[cn];
        }
        __syncthreads();
    }
#pragma unroll
    for (int r = 0; r < 4; ++r) {
        const size_t idx = (size_t)(i0 + (ty << 2) + r) * 512 + j0 + (tx << 2);
        float4 v;
        v.x = alpha * acc[r][0];
        v.y = alpha * acc[r][1];
        v.z = alpha * acc[r][2];
        v.w = alpha * acc[r][3];
        if (D) {
            const float4 d = *(const float4*)(D + idx);
            v.x += beta * d.x; v.y += beta * d.y; v.z += beta * d.z; v.w += beta * d.w;
        }
        *(float4*)(C + idx) = v;
    }
}

__global__ __launch_bounds__(256) void whiten_kernel(const float* __restrict__ X,
                                                     const float* __restrict__ P,
                                                     const float* __restrict__ wmm,
                                                     const float* __restrict__ scal,
                                                     float* __restrict__ out) {
    const int c0 = blockIdx.x << 6;
    const int h0 = blockIdx.y << 6;
    const int n  = blockIdx.z;
    const int t  = threadIdx.x;
    const int tx = t & 15, ty = t >> 4;
    __shared__ float Ps[64][33];
    __shared__ float Xs[32][65];
    float acc[4][4] = {};
    const int lcA = t & 31, lrA = t >> 5;
    const int lcB = t & 63, lrB = t >> 6;
    const float* Xn = X + (size_t)n * CHW;
    for (int k0 = 0; k0 < 512; k0 += 32) {
#pragma unroll
        for (int r = 0; r < 8; ++r) {
            const int row = lrA + (r << 3);
            Ps[row][lcA] = P[(size_t)(c0 + row) * 512 + k0 + lcA];
        }
#pragma unroll
        for (int r = 0; r < 8; ++r) {
            const int row = lrB + (r << 2);
            Xs[row][lcB] = Xn[(size_t)(k0 + row) * HWs + h0 + lcB];
        }
        __syncthreads();
#pragma unroll
        for (int k = 0; k < 32; ++k) {
            float a[4], b[4];
#pragma unroll
            for (int r = 0; r < 4; ++r) a[r] = Ps[(ty << 2) + r][k];
#pragma unroll
            for (int cn = 0; cn < 4; ++cn) b[cn] = Xs[k][(tx << 2) + cn];
#pragma unroll
            for (int r = 0; r < 4; ++r)
#pragma unroll
                for (int cn = 0; cn < 4; ++cn) acc[r][cn] += a[r] * b[cn];
        }
        __syncthreads();
    }
    const float sr = scal[1];
#pragma unroll
    for (int r = 0; r < 4; ++r) {
        const int c = c0 + (ty << 2) + r;
        const float wv = wmm[c];
        float4 v;
        v.x = sr * acc[r][0] - wv;
        v.y = sr * acc[r][1] - wv;
        v.z = sr * acc[r][2] - wv;
        v.w = sr * acc[r][3] - wv;
        *(float4*)(out + (size_t)n * CHW + (size_t)c * HWs + h0 + (tx << 2)) = v;
    }
}

// ---------------------------------------------------------------------------
extern "C" void kernel_launch(void* const* d_in, const int* in_sizes, int n_in,
                              void* d_out, int out_size, void* d_ws, size_t ws_size,
                              hipStream_t stream) {
    const float* X = (const float*)d_in[0];
    float* out     = (float*)d_out;

    const size_t NU16 = 33554432;   // CHW*Nn
    const size_t NM   = 262144;     // 512*512
    const size_t NEED = NU16 * 2 * 2                // Xbf + Xt
                      + NM * 10 * 2                 // 10 bf16 512x512 matrices
                      + (NM + 8192 + 512 + 512 + 16 + NM + NM) * 4;

    if (ws_size >= NEED) {
        u16* Xbf = (u16*)d_ws;
        u16* Xt  = Xbf + NU16;
        u16* Sh  = Xt  + NU16;
        u16* Sl  = Sh + NM;
        u16* Ph  = Sl + NM;
        u16* Pl  = Ph + NM;
        u16* Qh  = Pl + NM;
        u16* Ql  = Qh + NM;
        u16* T2h = Ql + NM;
        u16* T2l = T2h + NM;
        u16* T3h = T2l + NM;
        u16* T3l = T3h + NM;
        float* G     = (float*)(T3l + NM);
        float* meanP = G + NM;          // 16*512
        float* mean  = meanP + 8192;
        float* wmm   = mean + 512;
        float* scal  = wmm + 512;
        float* Pf    = scal + 16;
        float* Qf    = Pf + NM;

        hipMemsetAsync(G, 0, (NM + 8192) * sizeof(float), stream);  // G + meanP
        convert_transpose<<<dim3(16, 8, 64), 256, 0, stream>>>(X, Xbf, Xt, meanP);
        gram_mfma<<<320, 256, 0, stream>>>(Xbf, G);
        trace_kernel<<<1, 256, 0, stream>>>(G, meanP, mean, scal);
        sigman_kernel<<<1024, 256, 0, stream>>>(G, mean, scal, Sh, Sl, Pf, Ph, Pl);

        for (int it = 0; it < 5; ++it) {
            mm512s<<<64, 256, 0, stream>>>(Ph, Pl, Ph, Pl, 1.f, nullptr, 0.f,
                                           nullptr, T2h, T2l);                 // P2
            mm512s<<<64, 256, 0, stream>>>(T2h, T2l, Ph, Pl, 1.f, nullptr, 0.f,
                                           nullptr, T3h, T3l);                 // P3
            mm512s<<<64, 256, 0, stream>>>(T3h, T3l, Sh, Sl, -0.5f, Pf, 1.5f,
                                           Qf, Qh, Ql);                        // Pn
            { float* tf = Pf; Pf = Qf; Qf = tf; }
            { u16* th = Ph; Ph = Qh; Qh = th; }
            { u16* tl = Pl; Pl = Ql; Ql = tl; }
        }

        wmm_kernel<<<512, 128, 0, stream>>>(Pf, mean, scal, wmm);
        whiten_mfma<<<2048, 256, 0, stream>>>(Xt, Ph, wmm, scal, out);
    } else {
        // fallback: round-1 fp32 path (~6.3 MB ws)
        float* ws   = (float*)d_ws;
        float* mean = ws;
        float* wmm  = ws + 512;
        float* scal = ws + 1024;
        float* G    = ws + 2048;
        float* S    = G + 262144;
        float* Pa   = S + 262144;
        float* Pb   = Pa + 262144;
        float* P2   = Pb + 262144;
        float* P3   = P2 + 262144;

        mean_kernel<<<512, 256, 0, stream>>>(X, mean);
        hipMemsetAsync(G, 0, sizeof(float) * 262144, stream);
        gram_kernel<<<dim3(64, 8), 256, 0, stream>>>(X, G);
        trace_fb<<<1, 256, 0, stream>>>(G, mean, scal);
        sigman_full_kernel<<<1024, 256, 0, stream>>>(G, mean, scal, S, Pa);

        float* P  = Pa;
        float* Pn = Pb;
        for (int it = 0; it < 5; ++it) {
            mm512_kernel<<<64, 256, 0, stream>>>(P, P, P2, 1.f, nullptr, 0.f);
            mm512_kernel<<<64, 256, 0, stream>>>(P2, P, P3, 1.f, nullptr, 0.f);
            mm512_kernel<<<64, 256, 0, stream>>>(P3, S, Pn, -0.5f, P, 1.5f);
            float* tmp = P; P = Pn; Pn = tmp;
        }

        wmm_kernel<<<512, 128, 0, stream>>>(P, mean, scal, wmm);
        whiten_kernel<<<dim3(8, 16, 64), 256, 0, stream>>>(X, P, wmm, scal, out);
    }
}